// Round 13
// baseline (192.020 us; speedup 1.0000x reference)
//
#include <hip/hip_runtime.h>
#include <hip/hip_bf16.h>
#include <math.h>

// TreeLSTM, B=8, L=4096, D=300, H=128, 12 levels. Round 19:
// - R18 post-mortem: leaf still ~41us after GLDS B-staging + 2 blocks/CU ->
//   scalar-load theory dead. Leaf's remaining structural deltas vs the fast
//   level_ws shape: B-through-LDS, 5-iter K-loop w/ 10 barriers, in-loop
//   fp32 conversion. This round: leaf REBUILT in the exact level_ws anatomy:
//   * convx (R6-proven verbatim): x fp32 -> bf16 chunk-major [40][32768].
//   * leafws: grid (512,4); A staged ONCE (40KB LDS, 10 GLDS/wave);
//     Wfr[4][10] = 160 VGPR at kernel scope ((256,2) proven budget);
//     single K=320 pass; no inner barriers; h chunk + bf16-col-blocked c out.
// - Unchanged from R18: reorder (WcatC+WlfC), level_ws_t (nst 4/2/2/1...),
//   bf16 c hops leaf->lev1->lev2, single-block finish.

typedef __attribute__((ext_vector_type(8))) short bfrag8;   // 8 bf16 = 4 VGPRs
typedef __attribute__((ext_vector_type(4))) float f32x4;
typedef __attribute__((ext_vector_type(4))) short s16x4;

__device__ __forceinline__ float rcpf(float x) { return __builtin_amdgcn_rcpf(x); }
__device__ __forceinline__ float sigf(float x) { return rcpf(1.0f + __expf(-x)); }
__device__ __forceinline__ float tanh_f(float x) {
    float e = __expf(2.0f * x);              // x>>0: e=inf -> rcp=0 -> 1 ; x<<0: e=0 -> -1
    return 1.0f - 2.0f * rcpf(e + 1.0f);
}
__device__ __forceinline__ short f2bf(float f) {
    __hip_bfloat16 h = __float2bfloat16(f);
    return *reinterpret_cast<short*>(&h);
}
__device__ __forceinline__ float bf2f(short s) {
    union { unsigned int u; float f; } v;
    v.u = ((unsigned int)(unsigned short)s) << 16;
    return v.f;
}
#define GLDS(gp, lp) __builtin_amdgcn_global_load_lds( \
    (const __attribute__((address_space(1))) void*)(gp), \
    (__attribute__((address_space(3))) void*)(lp), 16, 0, 0)

// ---------------- weight reorder (once, tiny) ----------------
__global__ __launch_bounds__(256) void reorder_kernel(
    const float* __restrict__ W_l, const float* __restrict__ W_r,
    const float* __restrict__ W_leaf,
    short* __restrict__ Wcat_ch, short* __restrict__ Wleaf_ch)
{
    int idx = blockIdx.x * 256 + threadIdx.x;
    if (idx < 163840) {
        int n = idx >> 8, k = idx & 255;
        float v = (k < 128) ? W_l[k * 640 + n] : W_r[(k - 128) * 640 + n];
        Wcat_ch[(((size_t)(k >> 3)) * 640 + n) * 8 + (k & 7)] = f2bf(v);
        return;
    }
    idx -= 163840;
    if (idx < 81920) {
        int n = idx / 320, k = idx - n * 320;
        short v = (k < 300) ? f2bf(W_leaf[k * 256 + n]) : (short)0;
        Wleaf_ch[(((size_t)(k >> 3)) * 256 + n) * 8 + (k & 7)] = v;
    }
}

// ---------------- x fp32 [32768][300] -> xbf chunk-major [40][32768] units ----------------
// R6-proven verbatim.
__global__ __launch_bounds__(256) void convx_kernel(
    const float* __restrict__ x, short* __restrict__ xbf)
{
    __shared__ short Ls[64 * 328];
    const int tid = threadIdx.x;
    const int R0 = blockIdx.x * 64;
    for (int i = tid; i < 64 * 75; i += 256) {
        int r = i / 75, q = i - r * 75;
        f32x4 v = *(const f32x4*)(x + (size_t)(R0 + r) * 300 + q * 4);
        s16x4 o;
        #pragma unroll
        for (int t = 0; t < 4; ++t) o[t] = f2bf(v[t]);
        *(s16x4*)(Ls + r * 328 + q * 4) = o;
    }
    for (int i = tid; i < 64 * 20; i += 256) {
        int r = i / 20, q = i - r * 20;
        Ls[r * 328 + 300 + q] = 0;
    }
    __syncthreads();
    for (int i = tid; i < 40 * 64; i += 256) {
        int c = i >> 6, r = i & 63;
        bfrag8 v = *(const bfrag8*)(Ls + r * 328 + c * 8);
        *(bfrag8*)(xbf + ((size_t)c * 32768 + R0 + r) * 8) = v;
    }
}

// ---------------- leafws: [32768,320]@[320,256] in level_ws anatomy ----------------
// grid (512, 4): x = 64-row tile, y = 64-col slab. Wfr[4][10] = 160 VGPR at
// kernel scope; A (bf16 chunk) staged once, 10 GLDS/wave; single K=320 pass.
__global__ __launch_bounds__(256, 2) void leafws_kernel(
    const short* __restrict__ A,      // xbf [40][32768] units
    const short* __restrict__ Bw,     // WlfC [40][256] units
    const float* __restrict__ bleaf,
    short* __restrict__ hD,           // level-1 A, chunk layout [32][16384] units
    short* __restrict__ cDb)          // bf16 col-blocked [8][32768][16]
{
    __shared__ short Als[40 * 64 * 8];   // 40 KB, [c:0..40)[row:0..64)
    const int tid  = threadIdx.x;
    const int w    = tid >> 6, lane = tid & 63;
    const int quad = lane >> 4, l16 = lane & 15;
    const int j    = blockIdx.y;          // col slab [64j, 64j+64)
    const int tb   = blockIdx.x * 64;

    // stage A tile: 10 GLDS/wave (overlaps Wfr loads)
    #pragma unroll
    for (int t = 0; t < 10; ++t)
        GLDS(A + ((size_t)(t * 4 + w) * 32768 + tb + lane) * 8,
             (char*)Als + (t * 4 + w) * 1024);

    // W fragments: 4 col-groups x 10 k-chunks = 160 VGPR, loaded once
    bfrag8 Wfr[4][10];
    #pragma unroll
    for (int g = 0; g < 4; ++g)
        #pragma unroll
        for (int s = 0; s < 10; ++s)
            Wfr[g][s] = *(const bfrag8*)(Bw + ((size_t)(s * 4 + quad) * 256
                                               + j * 64 + g * 16 + l16) * 8);
    float bv[4];
    #pragma unroll
    for (int g = 0; g < 4; ++g) bv[g] = bleaf[j * 64 + g * 16 + l16];

    __syncthreads();

    // single K=320 pass: 10 s-steps x 4 MFMA
    f32x4 acc[4] = {};
    #pragma unroll
    for (int s = 0; s < 10; ++s) {
        bfrag8 af = *(const bfrag8*)(Als + ((s * 4 + quad) * 64 + w * 16 + l16) * 8);
        #pragma unroll
        for (int g = 0; g < 4; ++g)
            acc[g] = __builtin_amdgcn_mfma_f32_16x16x32_bf16(af, Wfr[g][s], acc[g], 0, 0, 0);
    }

    // epilogue: h (cols<128) chunk layout; c (cols>=128) bf16 col-blocked
    #pragma unroll
    for (int g = 0; g < 4; ++g) {
        int col = j * 64 + g * 16 + l16;
        #pragma unroll
        for (int rg = 0; rg < 4; ++rg) {
            int m = tb + w * 16 + quad * 4 + rg;
            float v = acc[g][rg] + bv[g];
            if (col < 128) {
                hD[(((size_t)((m & 1) * 16 + (col >> 3))) * 16384 + (m >> 1)) * 8
                   + (col & 7)] = f2bf(v);
            } else {
                int ch = col - 128;
                cDb[(size_t)(ch >> 4) * 32768 * 16 + (size_t)m * 16 + (ch & 15)]
                    = f2bf(v);
            }
        }
    }
}

// ---------------- weight-stationary level kernel (levels 1..8) ----------------
// PROVEN SHAPE: Wfr loaded ONCE at kernel scope. nst row-subtiles amortize.
// CIN_BF / COUT_BF select bf16 col-blocked c[j][rows][16] vs fp32 [rows][128].
template<int CIN_BF, int COUT_BF>
__global__ __launch_bounds__(256, 2) void level_ws_t(
    const short* __restrict__ A,      // [32][M] chunk units
    const void*  __restrict__ cprev,  // 2M rows
    const short* __restrict__ Wch,    // [32][640] chunk units
    const float* __restrict__ bias,   // [640]
    short* __restrict__ hout, void* __restrict__ cout_,  // M rows
    int M, int nst)
{
    __shared__ short Als[32 * 64 * 8];   // 32 KB, [c][row]
    const int tid  = threadIdx.x;
    const int w    = tid >> 6, lane = tid & 63;
    const int quad = lane >> 4, l16 = lane & 15;
    const int j   = blockIdx.y;
    const int tb0 = blockIdx.x * 64 * nst;
    const int h   = j * 16 + l16;

    // stage subtile 0 (overlaps the Wfr loads below)
    #pragma unroll
    for (int s = 0; s < 8; ++s)
        GLDS(A + ((size_t)(s * 4 + w) * M + tb0 + lane) * 8,
             (char*)Als + (s * 4 + w) * 1024);

    bfrag8 Wfr[5][8];
    #pragma unroll
    for (int g = 0; g < 5; ++g)
        #pragma unroll
        for (int s = 0; s < 8; ++s)
            Wfr[g][s] = *(const bfrag8*)(Wch + ((size_t)(s * 4 + quad) * 640
                                                + g * 128 + h) * 8);
    const float bi  = bias[h],       bfl = bias[128 + h], bfr_ = bias[256 + h];
    const float bo  = bias[384 + h], bg  = bias[512 + h];

    const int Mn = M >> 1;
    for (int st = 0; st < nst; ++st) {
        const int tb = tb0 + st * 64;
        __syncthreads();                 // staging of subtile st complete

        f32x4 acc[5] = {};
        #pragma unroll
        for (int s = 0; s < 8; ++s) {
            bfrag8 af = *(const bfrag8*)(Als + ((s * 4 + quad) * 64 + w * 16 + l16) * 8);
            #pragma unroll
            for (int g = 0; g < 5; ++g)
                acc[g] = __builtin_amdgcn_mfma_f32_16x16x32_bf16(af, Wfr[g][s], acc[g], 0, 0, 0);
        }

        if (st + 1 < nst) {
            __syncthreads();             // all Als reads done; restage
            #pragma unroll
            for (int s = 0; s < 8; ++s)
                GLDS(A + ((size_t)(s * 4 + w) * M + tb + 64 + lane) * 8,
                     (char*)Als + (s * 4 + w) * 1024);
        }

        #pragma unroll
        for (int rg = 0; rg < 4; ++rg) {
            int m = tb + w * 16 + quad * 4 + rg;
            float gi  = acc[0][rg] + bi;
            float gfl = acc[1][rg] + bfl;
            float gfr = acc[2][rg] + bfr_;
            float go  = acc[3][rg] + bo;
            float gg  = acc[4][rg] + bg;
            float cl, cr;
            if (CIN_BF) {
                const short* cp = (const short*)cprev;
                size_t base = (size_t)(h >> 4) * ((size_t)2 * M) * 16
                              + (size_t)(2 * m) * 16 + (h & 15);
                cl = bf2f(cp[base]);
                cr = bf2f(cp[base + 16]);
            } else {
                const float* cp = (const float*)cprev;
                cl = cp[(size_t)(2 * m) * 128 + h];
                cr = cp[(size_t)(2 * m + 1) * 128 + h];
            }
            float cn  = sigf(gfl) * cl + sigf(gfr) * cr + sigf(gi) * tanh_f(gg);
            float hn  = sigf(go) * tanh_f(cn);
            hout[(((size_t)((m & 1) * 16 + (h >> 3))) * Mn + (m >> 1)) * 8
                 + (h & 7)] = f2bf(hn);
            if (COUT_BF) {
                ((short*)cout_)[(size_t)(h >> 4) * (size_t)M * 16
                                + (size_t)m * 16 + (h & 15)] = f2bf(cn);
            } else {
                ((float*)cout_)[(size_t)m * 128 + h] = cn;
            }
        }
    }
}

// ---------------- single-block finisher: levels 9..12 ----------------
__global__ __launch_bounds__(512) void finish_kernel(
    const short* __restrict__ hin,   // [32][64] units (128-row chunk layout)
    const float* __restrict__ cin,   // [128][128] f32
    const short* __restrict__ Wch, const float* __restrict__ bias,
    float* __restrict__ out)         // [8][128]
{
    __shared__ short hP[32 * 64 * 8];   // 32 KB ping
    __shared__ short hQ[32 * 32 * 8];   // 16 KB pong
    __shared__ float cA[128 * 128];     // 64 KB
    __shared__ float cB[64 * 128];      // 32 KB
    const int tid  = threadIdx.x;
    const int w    = tid >> 6, lane = tid & 63;
    const int quad = lane >> 4, l16 = lane & 15;
    const int h    = w * 16 + l16;      // wave = h-group

    #pragma unroll
    for (int g = 0; g < 4; ++g)
        GLDS(hin + ((size_t)((g * 8 + w) * 64 + lane)) * 8,
             (char*)hP + ((g * 8 + w) * 64) * 16);
    #pragma unroll
    for (int g = 0; g < 8; ++g)
        GLDS(cin + ((size_t)((g * 8 + w) * 64 + lane)) * 4,
             (char*)cA + ((g * 8 + w) * 64) * 16);

    bfrag8 Wfr[5][8];
    #pragma unroll
    for (int g = 0; g < 5; ++g)
        #pragma unroll
        for (int s = 0; s < 8; ++s)
            Wfr[g][s] = *(const bfrag8*)(Wch + ((size_t)(s * 4 + quad) * 640
                                                + g * 128 + h) * 8);
    const float bi  = bias[h],       bfl = bias[128 + h], bfr_ = bias[256 + h];
    const float bo  = bias[384 + h], bg  = bias[512 + h];

    __syncthreads();

    #pragma unroll
    for (int t = 0; t < 4; ++t) {              // levels 9..12
        const int Mo = 64 >> t;                // 64, 32, 16, 8
        const short* hsrc = (t & 1) ? hQ : hP;
        short* hdst       = (t & 1) ? hP : hQ;
        const float* cread  = (t & 1) ? cB : cA;
        float*       cwrite = (t & 1) ? cA : cB;
        const int nrt = (Mo + 15) >> 4;

        for (int rt = 0; rt < nrt; ++rt) {
            f32x4 acc[5] = {};
            #pragma unroll
            for (int s = 0; s < 8; ++s) {
                bfrag8 af = *(const bfrag8*)(hsrc + ((s * 4 + quad) * Mo
                                                     + rt * 16 + l16) * 8);
                #pragma unroll
                for (int g = 0; g < 5; ++g)
                    acc[g] = __builtin_amdgcn_mfma_f32_16x16x32_bf16(
                                 af, Wfr[g][s], acc[g], 0, 0, 0);
            }
            #pragma unroll
            for (int rg = 0; rg < 4; ++rg) {
                int m = rt * 16 + quad * 4 + rg;
                if (m < Mo) {
                    float gi  = acc[0][rg] + bi;
                    float gfl = acc[1][rg] + bfl;
                    float gfr = acc[2][rg] + bfr_;
                    float go  = acc[3][rg] + bo;
                    float gg  = acc[4][rg] + bg;
                    float cl  = cread[(2 * m) * 128 + h];
                    float cr  = cread[(2 * m + 1) * 128 + h];
                    float cn  = sigf(gfl) * cl + sigf(gfr) * cr + sigf(gi) * tanh_f(gg);
                    float hn  = sigf(go) * tanh_f(cn);
                    if (t == 3) {
                        out[(size_t)m * 128 + h] = hn;
                    } else {
                        hdst[(((m & 1) * 16 + (h >> 3)) * (Mo >> 1) + (m >> 1)) * 8
                             + (h & 7)] = f2bf(hn);
                        cwrite[m * 128 + h] = cn;
                    }
                }
            }
        }
        __syncthreads();
    }
}

extern "C" void kernel_launch(void* const* d_in, const int* in_sizes, int n_in,
                              void* d_out, int out_size, void* d_ws, size_t ws_size,
                              hipStream_t stream)
{
    const float* x      = (const float*)d_in[0];
    const float* W_leaf = (const float*)d_in[1];
    const float* b_leaf = (const float*)d_in[2];
    const float* W_l    = (const float*)d_in[3];
    const float* W_r    = (const float*)d_in[4];
    const float* b      = (const float*)d_in[5];
    float* out = (float*)d_out;

    // workspace (~59.4 MB)
    char* p = (char*)d_ws;
    short* xbf   = (short*)p; p += (size_t)40 * 32768 * 16;        // 21.0 MB
    short* hA    = (short*)p; p += (size_t)32 * 16384 * 16 + 1024; //  8.4 MB
    short* hB    = (short*)p; p += (size_t)32 * 8192 * 16 + 1024;  //  4.2 MB
    char*  c0    = p;         p += (size_t)32768 * 128 * 4;        // 16.8 MB
    char*  c1    = p;         p += (size_t)16384 * 128 * 4;        //  8.4 MB
    short* WcatC = (short*)p; p += (size_t)32 * 640 * 16;          // 320 KB
    short* WlfC  = (short*)p; p += (size_t)40 * 256 * 16;          // 160 KB

    // 1) reorder: WcatC + bf16 WlfC (tiny)
    reorder_kernel<<<960, 256, 0, stream>>>(W_l, W_r, W_leaf, WcatC, WlfC);
    // 2) convx: x -> bf16 chunk-major
    convx_kernel<<<512, 256, 0, stream>>>(x, xbf);
    // 3) leafws: h -> hA, c -> c0 bf16 col-blocked
    leafws_kernel<<<dim3(512, 4), 256, 0, stream>>>(
        xbf, WlfC, b_leaf, hA, (short*)c0);

    // 4) lev1: cin bf16 (c0), cout bf16 (c1); M=16384, nst=4
    level_ws_t<1, 1><<<dim3(16384 / 256, 8), 256, 0, stream>>>(
        hA, c0, WcatC, b, hB, c1, 16384, 4);
    // 5) lev2: cin bf16 (c1), cout fp32 (c0); M=8192, nst=2
    level_ws_t<1, 0><<<dim3(8192 / 128, 8), 256, 0, stream>>>(
        hB, c1, WcatC, b, hA, c0, 8192, 2);

    // 6..11) levels 3..8 fp32 c; lev3 nst=2, rest nst=1
    const short* hin = hA; const char* cin = c0;
    int M = 4096;
    for (int lev = 3; lev <= 8; ++lev) {
        short* ho = (lev & 1) ? hB : hA;
        char*  co = (lev & 1) ? c1 : c0;
        int nst = (lev == 3) ? 2 : 1;
        level_ws_t<0, 0><<<dim3(M / (64 * nst), 8), 256, 0, stream>>>(
            hin, cin, WcatC, b, ho, co, M, nst);
        hin = ho; cin = co;
        M >>= 1;
    }
    // after lev8: hin = hA ([32][64] units), cin = c0 ([128][128] fp32)

    // 12) levels 9..12: single-block finisher
    finish_kernel<<<1, 512, 0, stream>>>(hA, (const float*)c0, WcatC, b, out);
}

// Round 14
// 170.935 us; speedup vs baseline: 1.1234x; 1.1234x over previous
//
#include <hip/hip_runtime.h>
#include <hip/hip_bf16.h>
#include <math.h>

// TreeLSTM, B=8, L=4096, D=300, H=128, 12 levels. Round 20:
// - R19 post-mortem: convx/leafws regressed (reverted). THE FIND: finish_kernel
//   has been ~43us ALL SESSION (hidden under 42us harness fills): 512-thr
//   kernels get only 128 VGPRs (also R10's 124), so Wfr[5][8]=160 never fit ->
//   W rematerialized from L2 inside the MFMA chain every iteration.
//   Sharpened law: 160-VGPR weight-stationary arrays ONLY live in 256-thr
//   (256,2) kernels; 512-thr kernels must keep register state under ~128.
// - finish-v2: loop s->g with ONE short-lived W fragment per (g,s) loaded
//   right before its 2 MFMAs (compile-time indices; acc[5][2]+af+W ~ 90 VGPR).
//   W re-reads remain but pipeline between independent MFMAs.
// - Rest = R18 exactly (best 166.2): reorder, leaf (GLDS B-staging, 512x64),
//   level_ws_t nst 4/2/2/1..., bf16 col-blocked c hops, same workspace.

typedef __attribute__((ext_vector_type(8))) short bfrag8;   // 8 bf16 = 4 VGPRs
typedef __attribute__((ext_vector_type(4))) float f32x4;

__device__ __forceinline__ float rcpf(float x) { return __builtin_amdgcn_rcpf(x); }
__device__ __forceinline__ float sigf(float x) { return rcpf(1.0f + __expf(-x)); }
__device__ __forceinline__ float tanh_f(float x) {
    float e = __expf(2.0f * x);              // x>>0: e=inf -> rcp=0 -> 1 ; x<<0: e=0 -> -1
    return 1.0f - 2.0f * rcpf(e + 1.0f);
}
__device__ __forceinline__ short f2bf(float f) {
    __hip_bfloat16 h = __float2bfloat16(f);
    return *reinterpret_cast<short*>(&h);
}
__device__ __forceinline__ float bf2f(short s) {
    union { unsigned int u; float f; } v;
    v.u = ((unsigned int)(unsigned short)s) << 16;
    return v.f;
}
__device__ __forceinline__ bfrag8 pack8(f32x4 a, f32x4 b) {
    union { int i[4]; bfrag8 v; } u;
    asm("v_cvt_pk_bf16_f32 %0, %1, %2" : "=v"(u.i[0]) : "v"(a[0]), "v"(a[1]));
    asm("v_cvt_pk_bf16_f32 %0, %1, %2" : "=v"(u.i[1]) : "v"(a[2]), "v"(a[3]));
    asm("v_cvt_pk_bf16_f32 %0, %1, %2" : "=v"(u.i[2]) : "v"(b[0]), "v"(b[1]));
    asm("v_cvt_pk_bf16_f32 %0, %1, %2" : "=v"(u.i[3]) : "v"(b[2]), "v"(b[3]));
    return u.v;
}
#define GLDS(gp, lp) __builtin_amdgcn_global_load_lds( \
    (const __attribute__((address_space(1))) void*)(gp), \
    (__attribute__((address_space(3))) void*)(lp), 16, 0, 0)

// ---------------- weight reorder (once, tiny) ----------------
__global__ __launch_bounds__(256) void reorder_kernel(
    const float* __restrict__ W_l, const float* __restrict__ W_r,
    const float* __restrict__ W_leaf,
    short* __restrict__ Wcat_ch, short* __restrict__ Wleaf_ch)
{
    int idx = blockIdx.x * 256 + threadIdx.x;
    if (idx < 163840) {
        int n = idx >> 8, k = idx & 255;
        float v = (k < 128) ? W_l[k * 640 + n] : W_r[(k - 128) * 640 + n];
        Wcat_ch[(((size_t)(k >> 3)) * 640 + n) * 8 + (k & 7)] = f2bf(v);
        return;
    }
    idx -= 163840;
    if (idx < 81920) {
        int n = idx / 320, k = idx - n * 320;
        short v = (k < 300) ? f2bf(W_leaf[k * 256 + n]) : (short)0;
        Wleaf_ch[(((size_t)(k >> 3)) * 256 + n) * 8 + (k & 7)] = v;
    }
}

// ---------------- leaf: [32768,320fp32]@[320,256] + bias, split h/c ----------------
// 512 blocks x 64 rows (2 blocks/CU); each block computes ALL 256 cols.
__global__ __launch_bounds__(256) void leaf_kernel(
    const float* __restrict__ x,   const short* __restrict__ Bw,
    const float* __restrict__ bleaf,
    short* __restrict__ hD,       // level-1 A, chunk layout [32][16384] units
    short* __restrict__ cDb)      // bf16 col-blocked [8][32768][16]
{
    __shared__ float Als[64 * 64];      // 16 KB: [row][16 units], src-swizzled
    __shared__ short Bls[8 * 256 * 8];  // 32 KB: [c][n 0..256) units
    const int tid  = threadIdx.x;
    const int w    = tid >> 6, lane = tid & 63;
    const int quad = lane >> 4, l16 = lane & 15;
    const int mBlk = blockIdx.x * 64;
    const int waveN = w * 64;           // col-quarter

    f32x4 acc[4][4] = {};
    const f32x4 zero4 = {0.f, 0.f, 0.f, 0.f};

    for (int c = 0; c < 5; ++c) {           // K = 5 * 64 = 320 (300 + zero pad)
        const int k0c = c * 64;
        // ---- stage A (x) as fp32, XOR-swizzled source, linear LDS ----
        {
            const int q_lds = lane & 15;
            const int rsub  = lane >> 4;
            #pragma unroll
            for (int g = 0; g < 4; ++g) {
                int row = w * 16 + g * 4 + rsub;
                int q_g = (q_lds & 8) | ((q_lds & 7) ^ (row & 7));
                if (c < 4 || q_g < 11) {
                    GLDS(x + (size_t)(mBlk + row) * 300 + k0c + q_g * 4,
                         (char*)Als + (w * 16 + g * 4) * 256);
                } else {
                    *(f32x4*)((char*)Als + row * 256 + q_lds * 16) = zero4;  // pad k=300..319
                }
            }
        }
        // ---- stage B from WlfC: 8 GLDS/wave (2048 units) ----
        #pragma unroll
        for (int g = 0; g < 8; ++g) {
            int i   = w * 8 + g;                // 0..31
            int cc  = i >> 2, colg = (i & 3) * 64;
            GLDS(Bw + ((size_t)(c * 8 + cc) * 256 + colg + lane) * 8,
                 (char*)Bls + ((cc * 256 + colg)) * 16);
        }
        __syncthreads();
        #pragma unroll
        for (int ks = 0; ks < 2; ++ks) {
            const int ca = ks * 4 + quad;
            bfrag8 af[4], bf4[4];
            #pragma unroll
            for (int i = 0; i < 4; ++i) {
                int r  = i * 16 + l16;
                int u0 = 2 * ca, u1 = 2 * ca + 1;
                int s0 = (u0 & 8) | ((u0 & 7) ^ (r & 7));
                int s1 = (u1 & 8) | ((u1 & 7) ^ (r & 7));
                f32x4 a0 = *(const f32x4*)(Als + r * 64 + s0 * 4);
                f32x4 a1 = *(const f32x4*)(Als + r * 64 + s1 * 4);
                af[i] = pack8(a0, a1);
            }
            #pragma unroll
            for (int jn = 0; jn < 4; ++jn)
                bf4[jn] = *(const bfrag8*)(Bls + (ca * 256 + waveN + jn * 16 + l16) * 8);
            #pragma unroll
            for (int i = 0; i < 4; ++i)
                #pragma unroll
                for (int jn = 0; jn < 4; ++jn)
                    acc[i][jn] = __builtin_amdgcn_mfma_f32_16x16x32_bf16(
                                     af[i], bf4[jn], acc[i][jn], 0, 0, 0);
        }
        __syncthreads();
    }

    #pragma unroll
    for (int i = 0; i < 4; ++i) {
        int row0 = mBlk + i * 16 + quad * 4;
        #pragma unroll
        for (int jn = 0; jn < 4; ++jn) {
            int col = waveN + jn * 16 + l16;
            float bv = bleaf[col];
            #pragma unroll
            for (int rg = 0; rg < 4; ++rg) {
                float v = acc[i][jn][rg] + bv;
                int m = row0 + rg;
                if (col < 128) {
                    int hc = col;
                    hD[(((size_t)((m & 1) * 16 + (hc >> 3))) * 16384 + (m >> 1)) * 8
                       + (hc & 7)] = f2bf(v);
                } else {
                    int ch = col - 128;
                    cDb[(size_t)(ch >> 4) * 32768 * 16 + (size_t)m * 16 + (ch & 15)]
                        = f2bf(v);
                }
            }
        }
    }
}

// ---------------- weight-stationary level kernel (levels 1..8) ----------------
// PROVEN SHAPE: Wfr loaded ONCE at kernel scope, 256 thr (256,2). nst amortizes.
template<int CIN_BF, int COUT_BF>
__global__ __launch_bounds__(256, 2) void level_ws_t(
    const short* __restrict__ A,      // [32][M] chunk units
    const void*  __restrict__ cprev,  // 2M rows
    const short* __restrict__ Wch,    // [32][640] chunk units
    const float* __restrict__ bias,   // [640]
    short* __restrict__ hout, void* __restrict__ cout_,  // M rows
    int M, int nst)
{
    __shared__ short Als[32 * 64 * 8];   // 32 KB, [c][row]
    const int tid  = threadIdx.x;
    const int w    = tid >> 6, lane = tid & 63;
    const int quad = lane >> 4, l16 = lane & 15;
    const int j   = blockIdx.y;
    const int tb0 = blockIdx.x * 64 * nst;
    const int h   = j * 16 + l16;

    // stage subtile 0 (overlaps the Wfr loads below)
    #pragma unroll
    for (int s = 0; s < 8; ++s)
        GLDS(A + ((size_t)(s * 4 + w) * M + tb0 + lane) * 8,
             (char*)Als + (s * 4 + w) * 1024);

    bfrag8 Wfr[5][8];
    #pragma unroll
    for (int g = 0; g < 5; ++g)
        #pragma unroll
        for (int s = 0; s < 8; ++s)
            Wfr[g][s] = *(const bfrag8*)(Wch + ((size_t)(s * 4 + quad) * 640
                                                + g * 128 + h) * 8);
    const float bi  = bias[h],       bfl = bias[128 + h], bfr_ = bias[256 + h];
    const float bo  = bias[384 + h], bg  = bias[512 + h];

    const int Mn = M >> 1;
    for (int st = 0; st < nst; ++st) {
        const int tb = tb0 + st * 64;
        __syncthreads();                 // staging of subtile st complete

        f32x4 acc[5] = {};
        #pragma unroll
        for (int s = 0; s < 8; ++s) {
            bfrag8 af = *(const bfrag8*)(Als + ((s * 4 + quad) * 64 + w * 16 + l16) * 8);
            #pragma unroll
            for (int g = 0; g < 5; ++g)
                acc[g] = __builtin_amdgcn_mfma_f32_16x16x32_bf16(af, Wfr[g][s], acc[g], 0, 0, 0);
        }

        if (st + 1 < nst) {
            __syncthreads();             // all Als reads done; restage
            #pragma unroll
            for (int s = 0; s < 8; ++s)
                GLDS(A + ((size_t)(s * 4 + w) * M + tb + 64 + lane) * 8,
                     (char*)Als + (s * 4 + w) * 1024);
        }

        #pragma unroll
        for (int rg = 0; rg < 4; ++rg) {
            int m = tb + w * 16 + quad * 4 + rg;
            float gi  = acc[0][rg] + bi;
            float gfl = acc[1][rg] + bfl;
            float gfr = acc[2][rg] + bfr_;
            float go  = acc[3][rg] + bo;
            float gg  = acc[4][rg] + bg;
            float cl, cr;
            if (CIN_BF) {
                const short* cp = (const short*)cprev;
                size_t base = (size_t)(h >> 4) * ((size_t)2 * M) * 16
                              + (size_t)(2 * m) * 16 + (h & 15);
                cl = bf2f(cp[base]);
                cr = bf2f(cp[base + 16]);
            } else {
                const float* cp = (const float*)cprev;
                cl = cp[(size_t)(2 * m) * 128 + h];
                cr = cp[(size_t)(2 * m + 1) * 128 + h];
            }
            float cn  = sigf(gfl) * cl + sigf(gfr) * cr + sigf(gi) * tanh_f(gg);
            float hn  = sigf(go) * tanh_f(cn);
            hout[(((size_t)((m & 1) * 16 + (h >> 3))) * Mn + (m >> 1)) * 8
                 + (h & 7)] = f2bf(hn);
            if (COUT_BF) {
                ((short*)cout_)[(size_t)(h >> 4) * (size_t)M * 16
                                + (size_t)m * 16 + (h & 15)] = f2bf(cn);
            } else {
                ((float*)cout_)[(size_t)m * 128 + h] = cn;
            }
        }
    }
}

// ---------------- single-block finisher v2: levels 9..12, <=128 VGPR ----------------
// 512 thr get only ~128 VGPRs -> Wfr[5][8] (160) can NEVER be resident here.
// v2: loop s -> g with ONE short-lived W fragment per (g,s), loaded right
// before its 2 MFMAs. acc[5][2] (40) + af (8) + in-flight W ~ 90 VGPR.
// All array indices compile-time (full unroll); t/pr loops kept rolled.
__global__ __launch_bounds__(512) void finish_kernel(
    const short* __restrict__ hin,   // [32][64] units (128-row chunk layout)
    const float* __restrict__ cin,   // [128][128] f32
    const short* __restrict__ Wch, const float* __restrict__ bias,
    float* __restrict__ out)         // [8][128]
{
    __shared__ short hP[32 * 64 * 8];   // 32 KB ping
    __shared__ short hQ[32 * 32 * 8];   // 16 KB pong
    __shared__ float cA[128 * 128];     // 64 KB
    __shared__ float cB[64 * 128];      // 32 KB
    const int tid  = threadIdx.x;
    const int w    = tid >> 6, lane = tid & 63;
    const int quad = lane >> 4, l16 = lane & 15;
    const int h    = w * 16 + l16;      // wave = h-group

    #pragma unroll
    for (int g = 0; g < 4; ++g)
        GLDS(hin + ((size_t)((g * 8 + w) * 64 + lane)) * 8,
             (char*)hP + ((g * 8 + w) * 64) * 16);
    #pragma unroll
    for (int g = 0; g < 8; ++g)
        GLDS(cin + ((size_t)((g * 8 + w) * 64 + lane)) * 4,
             (char*)cA + ((g * 8 + w) * 64) * 16);

    const float bi  = bias[h],       bfl = bias[128 + h], bfr_ = bias[256 + h];
    const float bo  = bias[384 + h], bg  = bias[512 + h];

    __syncthreads();

    #pragma unroll 1
    for (int t = 0; t < 4; ++t) {              // levels 9..12
        const int Mo = 64 >> t;                // 64, 32, 16, 8
        const short* hsrc = (t & 1) ? hQ : hP;
        short* hdst       = (t & 1) ? hP : hQ;
        const float* cread  = (t & 1) ? cB : cA;
        float*       cwrite = (t & 1) ? cA : cB;
        const int nrt   = (Mo + 15) >> 4;
        const int npair = (nrt + 1) >> 1;

        #pragma unroll 1
        for (int pr = 0; pr < npair; ++pr) {
            const int rt0 = pr * 2, rt1 = pr * 2 + 1;
            f32x4 acc[5][2] = {};
            #pragma unroll
            for (int s = 0; s < 8; ++s) {
                // rt1 reads may exceed the live region but stay inside the
                // LDS arrays (max offset < buffer size); results masked at write.
                bfrag8 af0 = *(const bfrag8*)(hsrc + ((s * 4 + quad) * Mo
                                                      + rt0 * 16 + l16) * 8);
                bfrag8 af1 = *(const bfrag8*)(hsrc + ((s * 4 + quad) * Mo
                                                      + rt1 * 16 + l16) * 8);
                #pragma unroll
                for (int g = 0; g < 5; ++g) {
                    bfrag8 Wt = *(const bfrag8*)(Wch + ((size_t)(s * 4 + quad) * 640
                                                        + g * 128 + h) * 8);
                    acc[g][0] = __builtin_amdgcn_mfma_f32_16x16x32_bf16(
                                    af0, Wt, acc[g][0], 0, 0, 0);
                    acc[g][1] = __builtin_amdgcn_mfma_f32_16x16x32_bf16(
                                    af1, Wt, acc[g][1], 0, 0, 0);
                }
            }
            #pragma unroll
            for (int r2 = 0; r2 < 2; ++r2) {
                int rt = pr * 2 + r2;
                if (rt < nrt) {
                    #pragma unroll
                    for (int rg = 0; rg < 4; ++rg) {
                        int m = rt * 16 + quad * 4 + rg;
                        if (m < Mo) {
                            float gi  = acc[0][r2][rg] + bi;
                            float gfl = acc[1][r2][rg] + bfl;
                            float gfr = acc[2][r2][rg] + bfr_;
                            float go  = acc[3][r2][rg] + bo;
                            float gg  = acc[4][r2][rg] + bg;
                            float cl  = cread[(2 * m) * 128 + h];
                            float cr  = cread[(2 * m + 1) * 128 + h];
                            float cn  = sigf(gfl) * cl + sigf(gfr) * cr
                                        + sigf(gi) * tanh_f(gg);
                            float hn  = sigf(go) * tanh_f(cn);
                            if (t == 3) {
                                out[(size_t)m * 128 + h] = hn;
                            } else {
                                hdst[(((m & 1) * 16 + (h >> 3)) * (Mo >> 1)
                                      + (m >> 1)) * 8 + (h & 7)] = f2bf(hn);
                                cwrite[m * 128 + h] = cn;
                            }
                        }
                    }
                }
            }
        }
        __syncthreads();
    }
}

extern "C" void kernel_launch(void* const* d_in, const int* in_sizes, int n_in,
                              void* d_out, int out_size, void* d_ws, size_t ws_size,
                              hipStream_t stream)
{
    const float* x      = (const float*)d_in[0];
    const float* W_leaf = (const float*)d_in[1];
    const float* b_leaf = (const float*)d_in[2];
    const float* W_l    = (const float*)d_in[3];
    const float* W_r    = (const float*)d_in[4];
    const float* b      = (const float*)d_in[5];
    float* out = (float*)d_out;

    // workspace (~38.4 MB)
    char* p = (char*)d_ws;
    short* hA    = (short*)p; p += (size_t)32 * 16384 * 16 + 1024; //  8.4 MB
    short* hB    = (short*)p; p += (size_t)32 * 8192 * 16 + 1024;  //  4.2 MB
    char*  c0    = p;         p += (size_t)32768 * 128 * 4;        // 16.8 MB
    char*  c1    = p;         p += (size_t)16384 * 128 * 4;        //  8.4 MB
    short* WcatC = (short*)p; p += (size_t)32 * 640 * 16;          // 320 KB
    short* WlfC  = (short*)p; p += (size_t)40 * 256 * 16;          // 160 KB

    // 1) reorder: WcatC + bf16 WlfC (tiny)
    reorder_kernel<<<960, 256, 0, stream>>>(W_l, W_r, W_leaf, WcatC, WlfC);

    // 2) leaf: 512 blocks x 64 rows; h -> hA, c -> c0 bf16 col-blocked
    leaf_kernel<<<512, 256, 0, stream>>>(x, WlfC, b_leaf, hA, (short*)c0);

    // 3) lev1: cin bf16 (c0), cout bf16 (c1); M=16384, nst=4
    level_ws_t<1, 1><<<dim3(16384 / 256, 8), 256, 0, stream>>>(
        hA, c0, WcatC, b, hB, c1, 16384, 4);
    // 4) lev2: cin bf16 (c1), cout fp32 (c0); M=8192, nst=2
    level_ws_t<1, 0><<<dim3(8192 / 128, 8), 256, 0, stream>>>(
        hB, c1, WcatC, b, hA, c0, 8192, 2);

    // 5..10) levels 3..8 fp32 c; lev3 nst=2, rest nst=1
    const short* hin = hA; const char* cin = c0;
    int M = 4096;
    for (int lev = 3; lev <= 8; ++lev) {
        short* ho = (lev & 1) ? hB : hA;
        char*  co = (lev & 1) ? c1 : c0;
        int nst = (lev == 3) ? 2 : 1;
        level_ws_t<0, 0><<<dim3(M / (64 * nst), 8), 256, 0, stream>>>(
            hin, cin, WcatC, b, ho, co, M, nst);
        hin = ho; cin = co;
        M >>= 1;
    }
    // after lev8: hin = hA ([32][64] units), cin = c0 ([128][128] fp32)

    // 11) levels 9..12: single-block finisher v2
    finish_kernel<<<1, 512, 0, stream>>>(hA, (const float*)c0, WcatC, b, out);
}